// Round 10
// baseline (263.476 us; speedup 1.0000x reference)
//
#include <hip/hip_runtime.h>
#include <hip/hip_bf16.h>

typedef unsigned short u16;
typedef unsigned int   u32;

using bf8 = __attribute__((ext_vector_type(8))) __bf16;
using f4  = __attribute__((ext_vector_type(4))) float;

__device__ __forceinline__ float b2f(u16 u) {
    union { u32 i; float f; } v; v.i = ((u32)u) << 16; return v.f;
}
__device__ __forceinline__ u16 f2b(float f) {
    union { float f; u32 i; } v; v.f = f;
    u32 x = v.i;
    x += 0x7fffu + ((x >> 16) & 1u);   // RNE
    return (u16)(x >> 16);
}
// Packed fp32x2 -> bf16x2 (low = first arg).
__device__ __forceinline__ u32 pk2(float lo, float hi) {
    union { __hip_bfloat162 h; u32 u; } v;
    v.h = __float22bfloat162_rn(make_float2(lo, hi));
    return v.u;
}

// ---------------------------------------------------------------------------
// Weight swizzle (verified layout — unchanged; frags used as A-operands):
// dst[((kt*16+ct)*64+lane)*8+j] = bf16(W[kt*32+(lane>>4)*8+j][ct*16+(lane&15)])
// ---------------------------------------------------------------------------
__global__ void swz_all(const float* __restrict__ w1, const float* __restrict__ w3,
                        const float* __restrict__ w2, const float* __restrict__ w4,
                        const float* __restrict__ w5, const float* __restrict__ w7,
                        u16* __restrict__ ws) {
    __shared__ u16 slab[32 * 270];
    int b = blockIdx.x, t = threadIdx.x;
    const float* src; u16* dst; int kmax, kt;
    if      (b <  2) { src = w1; dst = ws;          kmax = 54;  kt = b;      }
    else if (b <  4) { src = w3; dst = ws + 16384;  kmax = 54;  kt = b - 2;  }
    else if (b < 12) { src = w2; dst = ws + 32768;  kmax = 256; kt = b - 4;  }
    else if (b < 20) { src = w4; dst = ws + 98304;  kmax = 256; kt = b - 12; }
    else if (b < 28) { src = w5; dst = ws + 163840; kmax = 256; kt = b - 20; }
    else             { src = w7; dst = ws + 229376; kmax = 256; kt = b - 28; }

    #pragma unroll
    for (int it = 0; it < 8; ++it) {
        int flat = it * 1024 + t * 4;
        int row = flat >> 8, col = flat & 255;
        int k = kt * 32 + row;
        float4 v = make_float4(0.f, 0.f, 0.f, 0.f);
        if (k < kmax) v = *(const float4*)(src + k * 256 + col);
        u32* sp = (u32*)&slab[row * 270 + col];
        sp[0] = pk2(v.x, v.y);
        sp[1] = pk2(v.z, v.w);
    }
    __syncthreads();

    int lane = t & 63, wave = t >> 6, lr = lane & 15, kg = lane >> 4;
    #pragma unroll
    for (int i = 0; i < 4; ++i) {
        int ct = wave * 4 + i;
        u16 v[8];
        #pragma unroll
        for (int j = 0; j < 8; ++j)
            v[j] = slab[(kg * 8 + j) * 270 + ct * 16 + lr];
        uint4 o;
        o.x = (u32)v[0] | ((u32)v[1] << 16);
        o.y = (u32)v[2] | ((u32)v[3] << 16);
        o.z = (u32)v[4] | ((u32)v[5] << 16);
        o.w = (u32)v[6] | ((u32)v[7] << 16);
        *(uint4*)(dst + (size_t)(((kt * 16 + ct) * 64 + lane) * 8)) = o;
    }
}

// ---------------------------------------------------------------------------
// Fused critic, operand-swapped MFMA, 16 batch rows/WG (48 phi rows).
// A = swizzled weights (global/L2), B = activations (LDS b128).
// C/D per lane: batch=lane&15, hidden=lg*4+reg -> contiguous b64 epilogues.
// 256 threads, 4 waves, 4 hidden-tiles/wave, 3 row-tiles (pair p == rt).
// LDS pool (u16): inp [0,3456) 48x72; h [3456, 3456+48*264) stride 264.
// h reuse: S1 rows 0..15, S2 rows 16..31, RH0 rows 32..47, RH1 over S1.
// 32256 B/WG -> 4 blocks/CU, 16 waves/CU.
// ---------------------------------------------------------------------------
#define HS    264
#define H_OFF 3456
#define S2O   (16 * HS)
#define RH0O  (32 * HS)

__global__ __launch_bounds__(256, 4) void critic_kernel(
    const float* __restrict__ obs, const float* __restrict__ ag,
    const float* __restrict__ g,   const float* __restrict__ anchor,
    const float* __restrict__ act,
    const float* __restrict__ b1,  const float* __restrict__ b2,
    const float* __restrict__ b3,  const float* __restrict__ b4,
    const float* __restrict__ b5,  const float* __restrict__ b7,
    const float* __restrict__ w6,  const float* __restrict__ b6,
    const float* __restrict__ w8,  const float* __restrict__ b8,
    const u16* __restrict__ wsz, float* __restrict__ out, int B) {

    __shared__ u16 pool[H_OFF + 48 * HS];   // 16128 u16 = 32256 B

    const int t    = threadIdx.x;
    const int lane = t & 63;
    const int wave = t >> 6;
    const int lr   = lane & 15;
    const int lg   = lane >> 4;
    const int wg   = blockIdx.x;

    // ---- Gather: build pair inputs (48 rows x 54, pad to 64) ----
    if (t < 48) {
        const int O1[3] = {0, 0, 1}, O2[3] = {1, 2, 2};
        const int JA[3] = {3, 4, 6}, KA[3] = {5, 7, 8};
        int p = t / 16, bl = t % 16;
        int b = wg * 16 + bl;
        int j = JA[p], k = KA[p];
        bool sel = (anchor[b * 9 + j] - anchor[b * 9 + k]) >= 0.0f;
        int bit2 = sel ? j : k;
        int oi = sel ? O1[p] : O2[p];
        int oj = sel ? O2[p] : O1[p];
        u16* row = &pool[t * 72];
        row[0] = f2b(ag[b * 9 + p]);
        row[1] = f2b(ag[b * 9 + bit2]);
        row[2] = f2b(g[b * 9 + p]);
        row[3] = f2b(g[b * 9 + bit2]);
        for (int c = 0; c < 10; ++c) row[4 + c] = f2b(obs[b * 55 + c]);
        const u16 ONE = 0x3F80;
        row[14] = (oi == 0) ? ONE : 0; row[15] = (oi == 1) ? ONE : 0; row[16] = (oi == 2) ? ONE : 0;
        for (int c = 0; c < 15; ++c) row[17 + c] = f2b(obs[b * 55 + 10 + 15 * oi + c]);
        row[32] = (oj == 0) ? ONE : 0; row[33] = (oj == 1) ? ONE : 0; row[34] = (oj == 2) ? ONE : 0;
        for (int c = 0; c < 15; ++c) row[35 + c] = f2b(obs[b * 55 + 10 + 15 * oj + c]);
        for (int c = 0; c < 4; ++c)  row[50 + c] = f2b(act[b * 4 + c]);
        for (int c = 54; c < 64; ++c) row[c] = 0;
    }
    __syncthreads();

    u32 s1w[4][2];    // net0 pair-sums, packed bf16 (hidden-adjacent)
    u32 s2w[4][2];    // net1 pair-sums

    // ---- Phi networks (net 0: w1/w2, net 1: w3/w4) ----
    for (int net = 0; net < 2; ++net) {
        const u16* Wl1 = wsz + (net ? 16384 : 0);
        const u16* Wl2 = wsz + 32768 + (net ? 65536 : 0);
        const float* bl1 = net ? b3 : b1;
        const float* bl2 = net ? b4 : b2;

        // Layer 1: A=W1^T frags, B=inp rows (48 x 64 @ 64-k)
        f4 acc[3][4];
        #pragma unroll
        for (int rt = 0; rt < 3; ++rt)
            #pragma unroll
            for (int c = 0; c < 4; ++c) acc[rt][c] = (f4){0.f, 0.f, 0.f, 0.f};
        #pragma unroll
        for (int kt = 0; kt < 2; ++kt) {
            bf8 wfr[4];
            #pragma unroll
            for (int c = 0; c < 4; ++c)
                wfr[c] = *(const bf8*)(Wl1 + (size_t)(((kt * 16 + wave * 4 + c) * 64 + lane) * 8));
            #pragma unroll
            for (int rt = 0; rt < 3; ++rt) {
                bf8 xfr = *(const bf8*)(&pool[(rt * 16 + lr) * 72 + kt * 32 + lg * 8]);
                #pragma unroll
                for (int c = 0; c < 4; ++c)
                    acc[rt][c] = __builtin_amdgcn_mfma_f32_16x16x32_bf16(wfr[c], xfr, acc[rt][c], 0, 0, 0);
            }
        }
        #pragma unroll
        for (int c = 0; c < 4; ++c) {
            float4 bv = *(const float4*)(bl1 + (wave * 4 + c) * 16 + lg * 4);
            #pragma unroll
            for (int rt = 0; rt < 3; ++rt) {
                uint2 w;
                w.x = pk2(fmaxf(acc[rt][c][0] + bv.x, 0.f), fmaxf(acc[rt][c][1] + bv.y, 0.f));
                w.y = pk2(fmaxf(acc[rt][c][2] + bv.z, 0.f), fmaxf(acc[rt][c][3] + bv.w, 0.f));
                *(uint2*)&pool[H_OFF + (rt * 16 + lr) * HS + (wave * 4 + c) * 16 + lg * 4] = w;
            }
        }
        __syncthreads();

        // Layer 2: A=W2^T frags, B=h rows. Relu + pair-sum into regs.
        f4 acc2[3][4];
        #pragma unroll
        for (int rt = 0; rt < 3; ++rt)
            #pragma unroll
            for (int c = 0; c < 4; ++c) acc2[rt][c] = (f4){0.f, 0.f, 0.f, 0.f};
        #pragma unroll
        for (int ks = 0; ks < 8; ++ks) {
            bf8 wfr[4];
            #pragma unroll
            for (int c = 0; c < 4; ++c)
                wfr[c] = *(const bf8*)(Wl2 + (size_t)(((ks * 16 + wave * 4 + c) * 64 + lane) * 8));
            #pragma unroll
            for (int rt = 0; rt < 3; ++rt) {
                bf8 hfr = *(const bf8*)(&pool[H_OFF + (rt * 16 + lr) * HS + ks * 32 + lg * 8]);
                #pragma unroll
                for (int c = 0; c < 4; ++c)
                    acc2[rt][c] = __builtin_amdgcn_mfma_f32_16x16x32_bf16(wfr[c], hfr, acc2[rt][c], 0, 0, 0);
            }
        }
        #pragma unroll
        for (int c = 0; c < 4; ++c) {
            float4 bv = *(const float4*)(bl2 + (wave * 4 + c) * 16 + lg * 4);
            f4 sv = (f4){0.f, 0.f, 0.f, 0.f};
            #pragma unroll
            for (int p = 0; p < 3; ++p) {
                sv[0] += fmaxf(acc2[p][c][0] + bv.x, 0.f);
                sv[1] += fmaxf(acc2[p][c][1] + bv.y, 0.f);
                sv[2] += fmaxf(acc2[p][c][2] + bv.z, 0.f);
                sv[3] += fmaxf(acc2[p][c][3] + bv.w, 0.f);
            }
            if (net == 0) {
                s1w[c][0] = pk2(sv[0], sv[1]);
                s1w[c][1] = pk2(sv[2], sv[3]);
            } else {
                s2w[c][0] = pk2(sv[0], sv[1]);
                s2w[c][1] = pk2(sv[2], sv[3]);
            }
        }
        __syncthreads();  // h reads done before next net overwrites h
    }

    // ---- Write S1 (rows 0..15), S2 (rows 16..31): one b64 each ----
    #pragma unroll
    for (int c = 0; c < 4; ++c) {
        int base = H_OFF + lr * HS + (wave * 4 + c) * 16 + lg * 4;
        *(uint2*)&pool[base]       = *(uint2*)&s1w[c][0];
        *(uint2*)&pool[base + S2O] = *(uint2*)&s2w[c][0];
    }
    __syncthreads();

    // ---- Rho hidden layers, both nets in one MFMA phase ----
    {
        const u16* W5 = wsz + 163840;
        const u16* W7 = wsz + 229376;
        f4 racc[2][4];
        #pragma unroll
        for (int rt = 0; rt < 2; ++rt)
            #pragma unroll
            for (int c = 0; c < 4; ++c) racc[rt][c] = (f4){0.f, 0.f, 0.f, 0.f};
        #pragma unroll
        for (int ks = 0; ks < 8; ++ks) {
            bf8 w5f[4], w7f[4];
            #pragma unroll
            for (int c = 0; c < 4; ++c) {
                size_t off = (size_t)(((ks * 16 + wave * 4 + c) * 64 + lane) * 8);
                w5f[c] = *(const bf8*)(W5 + off);
                w7f[c] = *(const bf8*)(W7 + off);
            }
            bf8 s1f = *(const bf8*)(&pool[H_OFF + lr * HS + ks * 32 + lg * 8]);
            bf8 s2f = *(const bf8*)(&pool[H_OFF + S2O + lr * HS + ks * 32 + lg * 8]);
            #pragma unroll
            for (int c = 0; c < 4; ++c) {
                racc[0][c] = __builtin_amdgcn_mfma_f32_16x16x32_bf16(w5f[c], s1f, racc[0][c], 0, 0, 0);
                racc[1][c] = __builtin_amdgcn_mfma_f32_16x16x32_bf16(w7f[c], s2f, racc[1][c], 0, 0, 0);
            }
        }
        // net0 epilogue -> RH0 (rows 32..47; disjoint from S reads)
        #pragma unroll
        for (int c = 0; c < 4; ++c) {
            float4 bv = *(const float4*)(b5 + (wave * 4 + c) * 16 + lg * 4);
            uint2 w;
            w.x = pk2(fmaxf(racc[0][c][0] + bv.x, 0.f), fmaxf(racc[0][c][1] + bv.y, 0.f));
            w.y = pk2(fmaxf(racc[0][c][2] + bv.z, 0.f), fmaxf(racc[0][c][3] + bv.w, 0.f));
            *(uint2*)&pool[H_OFF + RH0O + lr * HS + (wave * 4 + c) * 16 + lg * 4] = w;
        }
        __syncthreads();   // all S1 reads done before net1 overwrites it
        // net1 epilogue -> RH1 (over consumed S1, rows 0..15)
        #pragma unroll
        for (int c = 0; c < 4; ++c) {
            float4 bv = *(const float4*)(b7 + (wave * 4 + c) * 16 + lg * 4);
            uint2 w;
            w.x = pk2(fmaxf(racc[1][c][0] + bv.x, 0.f), fmaxf(racc[1][c][1] + bv.y, 0.f));
            w.y = pk2(fmaxf(racc[1][c][2] + bv.z, 0.f), fmaxf(racc[1][c][3] + bv.w, 0.f));
            *(uint2*)&pool[H_OFF + lr * HS + (wave * 4 + c) * 16 + lg * 4] = w;
        }
        __syncthreads();
    }

    // ---- Final dots, 8-way split-K over 256 threads. FP32 OUT ----
    {
        int oidx = t & 31;             // net*16 + row
        int kc   = t >> 5;             // 0..7, 32 k-elems each
        int net  = oidx >> 4, r = oidx & 15;
        int hoff = net ? H_OFF : H_OFF + RH0O;
        const float* wv = net ? w8 : w6;
        float s = 0.f;
        int base = hoff + r * HS + kc * 32;
        #pragma unroll
        for (int it = 0; it < 8; ++it) {
            uint2 two = *(const uint2*)&pool[base + it * 4];
            float4 wq = *(const float4*)(wv + kc * 32 + it * 4);
            s += __uint_as_float(two.x << 16)          * wq.x;
            s += __uint_as_float(two.x & 0xffff0000u)  * wq.y;
            s += __uint_as_float(two.y << 16)          * wq.z;
            s += __uint_as_float(two.y & 0xffff0000u)  * wq.w;
        }
        __syncthreads();
        ((u32*)pool)[t] = __float_as_uint(s);   // partials in dead inp region
    }
    __syncthreads();
    if (t < 32) {
        int net = t >> 4, r = t & 15;
        float qv = net ? b8[0] : b6[0];
        #pragma unroll
        for (int kc = 0; kc < 8; ++kc)
            qv += __uint_as_float(((u32*)pool)[kc * 32 + t]);
        out[net * B + wg * 16 + r] = qv;
    }
}

extern "C" void kernel_launch(void* const* d_in, const int* in_sizes, int n_in,
                              void* d_out, int out_size, void* d_ws, size_t ws_size,
                              hipStream_t stream) {
    const float* obs = (const float*)d_in[0];
    const float* ag  = (const float*)d_in[1];
    const float* g   = (const float*)d_in[2];
    const float* anc = (const float*)d_in[3];
    const float* act = (const float*)d_in[4];
    const float* w1  = (const float*)d_in[5];
    const float* b1  = (const float*)d_in[6];
    const float* w2  = (const float*)d_in[7];
    const float* b2  = (const float*)d_in[8];
    const float* w3  = (const float*)d_in[9];
    const float* b3  = (const float*)d_in[10];
    const float* w4  = (const float*)d_in[11];
    const float* b4  = (const float*)d_in[12];
    const float* w5  = (const float*)d_in[13];
    const float* b5  = (const float*)d_in[14];
    const float* w6  = (const float*)d_in[15];
    const float* b6  = (const float*)d_in[16];
    const float* w7  = (const float*)d_in[17];
    const float* b7  = (const float*)d_in[18];
    const float* w8  = (const float*)d_in[19];
    const float* b8  = (const float*)d_in[20];
    u16* ws    = (u16*)d_ws;
    float* out = (float*)d_out;
    int B = in_sizes[0] / 55;

    swz_all<<<36, 256, 0, stream>>>(w1, w3, w2, w4, w5, w7, ws);
    critic_kernel<<<(B + 15) / 16, 256, 0, stream>>>(obs, ag, g, anc, act,
                                                     b1, b2, b3, b4, b5, b7,
                                                     w6, b6, w8, b8, ws, out, B);
}

// Round 11
// 228.416 us; speedup vs baseline: 1.1535x; 1.1535x over previous
//
#include <hip/hip_runtime.h>
#include <hip/hip_bf16.h>

typedef unsigned short u16;
typedef unsigned int   u32;

using bf8 = __attribute__((ext_vector_type(8))) __bf16;
using f4  = __attribute__((ext_vector_type(4))) float;

__device__ __forceinline__ float b2f(u16 u) {
    union { u32 i; float f; } v; v.i = ((u32)u) << 16; return v.f;
}
__device__ __forceinline__ u16 f2b(float f) {
    union { float f; u32 i; } v; v.f = f;
    u32 x = v.i;
    x += 0x7fffu + ((x >> 16) & 1u);   // RNE
    return (u16)(x >> 16);
}
// Packed fp32x2 -> bf16x2 (low = first arg).
__device__ __forceinline__ u32 pk2(float lo, float hi) {
    union { __hip_bfloat162 h; u32 u; } v;
    v.h = __float22bfloat162_rn(make_float2(lo, hi));
    return v.u;
}

// ---------------------------------------------------------------------------
// Weight swizzle (verified layout — unchanged; frags used as A-operands):
// dst[((kt*16+ct)*64+lane)*8+j] = bf16(W[kt*32+(lane>>4)*8+j][ct*16+(lane&15)])
// ---------------------------------------------------------------------------
__global__ void swz_all(const float* __restrict__ w1, const float* __restrict__ w3,
                        const float* __restrict__ w2, const float* __restrict__ w4,
                        const float* __restrict__ w5, const float* __restrict__ w7,
                        u16* __restrict__ ws) {
    __shared__ u16 slab[32 * 270];
    int b = blockIdx.x, t = threadIdx.x;
    const float* src; u16* dst; int kmax, kt;
    if      (b <  2) { src = w1; dst = ws;          kmax = 54;  kt = b;      }
    else if (b <  4) { src = w3; dst = ws + 16384;  kmax = 54;  kt = b - 2;  }
    else if (b < 12) { src = w2; dst = ws + 32768;  kmax = 256; kt = b - 4;  }
    else if (b < 20) { src = w4; dst = ws + 98304;  kmax = 256; kt = b - 12; }
    else if (b < 28) { src = w5; dst = ws + 163840; kmax = 256; kt = b - 20; }
    else             { src = w7; dst = ws + 229376; kmax = 256; kt = b - 28; }

    #pragma unroll
    for (int it = 0; it < 8; ++it) {
        int flat = it * 1024 + t * 4;
        int row = flat >> 8, col = flat & 255;
        int k = kt * 32 + row;
        float4 v = make_float4(0.f, 0.f, 0.f, 0.f);
        if (k < kmax) v = *(const float4*)(src + k * 256 + col);
        u32* sp = (u32*)&slab[row * 270 + col];
        sp[0] = pk2(v.x, v.y);
        sp[1] = pk2(v.z, v.w);
    }
    __syncthreads();

    int lane = t & 63, wave = t >> 6, lr = lane & 15, kg = lane >> 4;
    #pragma unroll
    for (int i = 0; i < 4; ++i) {
        int ct = wave * 4 + i;
        u16 v[8];
        #pragma unroll
        for (int j = 0; j < 8; ++j)
            v[j] = slab[(kg * 8 + j) * 270 + ct * 16 + lr];
        uint4 o;
        o.x = (u32)v[0] | ((u32)v[1] << 16);
        o.y = (u32)v[2] | ((u32)v[3] << 16);
        o.z = (u32)v[4] | ((u32)v[5] << 16);
        o.w = (u32)v[6] | ((u32)v[7] << 16);
        *(uint4*)(dst + (size_t)(((kt * 16 + ct) * 64 + lane) * 8)) = o;
    }
}

// ---------------------------------------------------------------------------
// Fused critic, operand-swapped MFMA, 16 batch rows/WG (48 phi rows).
// A = swizzled weights (global/L2), B = activations (LDS b128).
// C/D per lane: batch=lane&15, hidden=lg*4+reg -> contiguous b64 epilogues.
// 256 threads, 4 waves, 4 hidden-tiles/wave, 3 row-tiles (pair p == rt).
// LDS pool (u16): inp [0,3456) 48x72; h [3456, 3456+48*264) stride 264.
// h reuse: S1 rows 0..15, S2 rows 16..31, RH0 rows 32..47, RH1 over S1.
// 32256 B/WG -> 4 blocks/CU (LDS-limited), 16 waves/CU.
// __launch_bounds__(256,2): r8/r10 showed min-waves=4 forces a 64-VGPR
// allocation that spills (WRITE_SIZE 81/115 MB); (256,2) gives 128 VGPRs,
// no spill (r9), and 128*4 waves/SIMD still fits the 512-VGPR pool.
// ---------------------------------------------------------------------------
#define HS    264
#define H_OFF 3456
#define S2O   (16 * HS)
#define RH0O  (32 * HS)

__global__ __launch_bounds__(256, 2) void critic_kernel(
    const float* __restrict__ obs, const float* __restrict__ ag,
    const float* __restrict__ g,   const float* __restrict__ anchor,
    const float* __restrict__ act,
    const float* __restrict__ b1,  const float* __restrict__ b2,
    const float* __restrict__ b3,  const float* __restrict__ b4,
    const float* __restrict__ b5,  const float* __restrict__ b7,
    const float* __restrict__ w6,  const float* __restrict__ b6,
    const float* __restrict__ w8,  const float* __restrict__ b8,
    const u16* __restrict__ wsz, float* __restrict__ out, int B) {

    __shared__ u16 pool[H_OFF + 48 * HS];   // 16128 u16 = 32256 B

    const int t    = threadIdx.x;
    const int lane = t & 63;
    const int wave = t >> 6;
    const int lr   = lane & 15;
    const int lg   = lane >> 4;
    const int wg   = blockIdx.x;

    // ---- Gather: build pair inputs (48 rows x 54, pad to 64) ----
    if (t < 48) {
        const int O1[3] = {0, 0, 1}, O2[3] = {1, 2, 2};
        const int JA[3] = {3, 4, 6}, KA[3] = {5, 7, 8};
        int p = t / 16, bl = t % 16;
        int b = wg * 16 + bl;
        int j = JA[p], k = KA[p];
        bool sel = (anchor[b * 9 + j] - anchor[b * 9 + k]) >= 0.0f;
        int bit2 = sel ? j : k;
        int oi = sel ? O1[p] : O2[p];
        int oj = sel ? O2[p] : O1[p];
        u16* row = &pool[t * 72];
        row[0] = f2b(ag[b * 9 + p]);
        row[1] = f2b(ag[b * 9 + bit2]);
        row[2] = f2b(g[b * 9 + p]);
        row[3] = f2b(g[b * 9 + bit2]);
        for (int c = 0; c < 10; ++c) row[4 + c] = f2b(obs[b * 55 + c]);
        const u16 ONE = 0x3F80;
        row[14] = (oi == 0) ? ONE : 0; row[15] = (oi == 1) ? ONE : 0; row[16] = (oi == 2) ? ONE : 0;
        for (int c = 0; c < 15; ++c) row[17 + c] = f2b(obs[b * 55 + 10 + 15 * oi + c]);
        row[32] = (oj == 0) ? ONE : 0; row[33] = (oj == 1) ? ONE : 0; row[34] = (oj == 2) ? ONE : 0;
        for (int c = 0; c < 15; ++c) row[35 + c] = f2b(obs[b * 55 + 10 + 15 * oj + c]);
        for (int c = 0; c < 4; ++c)  row[50 + c] = f2b(act[b * 4 + c]);
        for (int c = 54; c < 64; ++c) row[c] = 0;
    }
    __syncthreads();

    u32 s1w[4][2];    // net0 pair-sums, packed bf16 (hidden-adjacent)
    u32 s2w[4][2];    // net1 pair-sums

    // ---- Phi networks (net 0: w1/w2, net 1: w3/w4) ----
    for (int net = 0; net < 2; ++net) {
        const u16* Wl1 = wsz + (net ? 16384 : 0);
        const u16* Wl2 = wsz + 32768 + (net ? 65536 : 0);
        const float* bl1 = net ? b3 : b1;
        const float* bl2 = net ? b4 : b2;

        // Layer 1: A=W1^T frags, B=inp rows (48 x 64 @ 64-k)
        f4 acc[3][4];
        #pragma unroll
        for (int rt = 0; rt < 3; ++rt)
            #pragma unroll
            for (int c = 0; c < 4; ++c) acc[rt][c] = (f4){0.f, 0.f, 0.f, 0.f};
        #pragma unroll
        for (int kt = 0; kt < 2; ++kt) {
            bf8 wfr[4];
            #pragma unroll
            for (int c = 0; c < 4; ++c)
                wfr[c] = *(const bf8*)(Wl1 + (size_t)(((kt * 16 + wave * 4 + c) * 64 + lane) * 8));
            #pragma unroll
            for (int rt = 0; rt < 3; ++rt) {
                bf8 xfr = *(const bf8*)(&pool[(rt * 16 + lr) * 72 + kt * 32 + lg * 8]);
                #pragma unroll
                for (int c = 0; c < 4; ++c)
                    acc[rt][c] = __builtin_amdgcn_mfma_f32_16x16x32_bf16(wfr[c], xfr, acc[rt][c], 0, 0, 0);
            }
        }
        #pragma unroll
        for (int c = 0; c < 4; ++c) {
            float4 bv = *(const float4*)(bl1 + (wave * 4 + c) * 16 + lg * 4);
            #pragma unroll
            for (int rt = 0; rt < 3; ++rt) {
                uint2 w;
                w.x = pk2(fmaxf(acc[rt][c][0] + bv.x, 0.f), fmaxf(acc[rt][c][1] + bv.y, 0.f));
                w.y = pk2(fmaxf(acc[rt][c][2] + bv.z, 0.f), fmaxf(acc[rt][c][3] + bv.w, 0.f));
                *(uint2*)&pool[H_OFF + (rt * 16 + lr) * HS + (wave * 4 + c) * 16 + lg * 4] = w;
            }
        }
        __syncthreads();

        // Layer 2: A=W2^T frags, B=h rows. Relu + pair-sum into regs.
        f4 acc2[3][4];
        #pragma unroll
        for (int rt = 0; rt < 3; ++rt)
            #pragma unroll
            for (int c = 0; c < 4; ++c) acc2[rt][c] = (f4){0.f, 0.f, 0.f, 0.f};
        #pragma unroll
        for (int ks = 0; ks < 8; ++ks) {
            bf8 wfr[4];
            #pragma unroll
            for (int c = 0; c < 4; ++c)
                wfr[c] = *(const bf8*)(Wl2 + (size_t)(((ks * 16 + wave * 4 + c) * 64 + lane) * 8));
            #pragma unroll
            for (int rt = 0; rt < 3; ++rt) {
                bf8 hfr = *(const bf8*)(&pool[H_OFF + (rt * 16 + lr) * HS + ks * 32 + lg * 8]);
                #pragma unroll
                for (int c = 0; c < 4; ++c)
                    acc2[rt][c] = __builtin_amdgcn_mfma_f32_16x16x32_bf16(wfr[c], hfr, acc2[rt][c], 0, 0, 0);
            }
        }
        #pragma unroll
        for (int c = 0; c < 4; ++c) {
            float4 bv = *(const float4*)(bl2 + (wave * 4 + c) * 16 + lg * 4);
            f4 sv = (f4){0.f, 0.f, 0.f, 0.f};
            #pragma unroll
            for (int p = 0; p < 3; ++p) {
                sv[0] += fmaxf(acc2[p][c][0] + bv.x, 0.f);
                sv[1] += fmaxf(acc2[p][c][1] + bv.y, 0.f);
                sv[2] += fmaxf(acc2[p][c][2] + bv.z, 0.f);
                sv[3] += fmaxf(acc2[p][c][3] + bv.w, 0.f);
            }
            if (net == 0) {
                s1w[c][0] = pk2(sv[0], sv[1]);
                s1w[c][1] = pk2(sv[2], sv[3]);
            } else {
                s2w[c][0] = pk2(sv[0], sv[1]);
                s2w[c][1] = pk2(sv[2], sv[3]);
            }
        }
        __syncthreads();  // h reads done before next net overwrites h
    }

    // ---- Write S1 (rows 0..15), S2 (rows 16..31): one b64 each ----
    #pragma unroll
    for (int c = 0; c < 4; ++c) {
        int base = H_OFF + lr * HS + (wave * 4 + c) * 16 + lg * 4;
        *(uint2*)&pool[base]       = *(uint2*)&s1w[c][0];
        *(uint2*)&pool[base + S2O] = *(uint2*)&s2w[c][0];
    }
    __syncthreads();

    // ---- Rho hidden layers, both nets in one MFMA phase ----
    {
        const u16* W5 = wsz + 163840;
        const u16* W7 = wsz + 229376;
        f4 racc[2][4];
        #pragma unroll
        for (int rt = 0; rt < 2; ++rt)
            #pragma unroll
            for (int c = 0; c < 4; ++c) racc[rt][c] = (f4){0.f, 0.f, 0.f, 0.f};
        #pragma unroll
        for (int ks = 0; ks < 8; ++ks) {
            bf8 w5f[4], w7f[4];
            #pragma unroll
            for (int c = 0; c < 4; ++c) {
                size_t off = (size_t)(((ks * 16 + wave * 4 + c) * 64 + lane) * 8);
                w5f[c] = *(const bf8*)(W5 + off);
                w7f[c] = *(const bf8*)(W7 + off);
            }
            bf8 s1f = *(const bf8*)(&pool[H_OFF + lr * HS + ks * 32 + lg * 8]);
            bf8 s2f = *(const bf8*)(&pool[H_OFF + S2O + lr * HS + ks * 32 + lg * 8]);
            #pragma unroll
            for (int c = 0; c < 4; ++c) {
                racc[0][c] = __builtin_amdgcn_mfma_f32_16x16x32_bf16(w5f[c], s1f, racc[0][c], 0, 0, 0);
                racc[1][c] = __builtin_amdgcn_mfma_f32_16x16x32_bf16(w7f[c], s2f, racc[1][c], 0, 0, 0);
            }
        }
        // net0 epilogue -> RH0 (rows 32..47; disjoint from S reads)
        #pragma unroll
        for (int c = 0; c < 4; ++c) {
            float4 bv = *(const float4*)(b5 + (wave * 4 + c) * 16 + lg * 4);
            uint2 w;
            w.x = pk2(fmaxf(racc[0][c][0] + bv.x, 0.f), fmaxf(racc[0][c][1] + bv.y, 0.f));
            w.y = pk2(fmaxf(racc[0][c][2] + bv.z, 0.f), fmaxf(racc[0][c][3] + bv.w, 0.f));
            *(uint2*)&pool[H_OFF + RH0O + lr * HS + (wave * 4 + c) * 16 + lg * 4] = w;
        }
        __syncthreads();   // all S1 reads done before net1 overwrites it
        // net1 epilogue -> RH1 (over consumed S1, rows 0..15)
        #pragma unroll
        for (int c = 0; c < 4; ++c) {
            float4 bv = *(const float4*)(b7 + (wave * 4 + c) * 16 + lg * 4);
            uint2 w;
            w.x = pk2(fmaxf(racc[1][c][0] + bv.x, 0.f), fmaxf(racc[1][c][1] + bv.y, 0.f));
            w.y = pk2(fmaxf(racc[1][c][2] + bv.z, 0.f), fmaxf(racc[1][c][3] + bv.w, 0.f));
            *(uint2*)&pool[H_OFF + lr * HS + (wave * 4 + c) * 16 + lg * 4] = w;
        }
        __syncthreads();
    }

    // ---- Final dots, 8-way split-K over 256 threads. FP32 OUT ----
    {
        int oidx = t & 31;             // net*16 + row
        int kc   = t >> 5;             // 0..7, 32 k-elems each
        int net  = oidx >> 4, r = oidx & 15;
        int hoff = net ? H_OFF : H_OFF + RH0O;
        const float* wv = net ? w8 : w6;
        float s = 0.f;
        int base = hoff + r * HS + kc * 32;
        #pragma unroll
        for (int it = 0; it < 8; ++it) {
            uint2 two = *(const uint2*)&pool[base + it * 4];
            float4 wq = *(const float4*)(wv + kc * 32 + it * 4);
            s += __uint_as_float(two.x << 16)          * wq.x;
            s += __uint_as_float(two.x & 0xffff0000u)  * wq.y;
            s += __uint_as_float(two.y << 16)          * wq.z;
            s += __uint_as_float(two.y & 0xffff0000u)  * wq.w;
        }
        __syncthreads();
        ((u32*)pool)[t] = __float_as_uint(s);   // partials in dead inp region
    }
    __syncthreads();
    if (t < 32) {
        int net = t >> 4, r = t & 15;
        float qv = net ? b8[0] : b6[0];
        #pragma unroll
        for (int kc = 0; kc < 8; ++kc)
            qv += __uint_as_float(((u32*)pool)[kc * 32 + t]);
        out[net * B + wg * 16 + r] = qv;
    }
}

extern "C" void kernel_launch(void* const* d_in, const int* in_sizes, int n_in,
                              void* d_out, int out_size, void* d_ws, size_t ws_size,
                              hipStream_t stream) {
    const float* obs = (const float*)d_in[0];
    const float* ag  = (const float*)d_in[1];
    const float* g   = (const float*)d_in[2];
    const float* anc = (const float*)d_in[3];
    const float* act = (const float*)d_in[4];
    const float* w1  = (const float*)d_in[5];
    const float* b1  = (const float*)d_in[6];
    const float* w2  = (const float*)d_in[7];
    const float* b2  = (const float*)d_in[8];
    const float* w3  = (const float*)d_in[9];
    const float* b3  = (const float*)d_in[10];
    const float* w4  = (const float*)d_in[11];
    const float* b4  = (const float*)d_in[12];
    const float* w5  = (const float*)d_in[13];
    const float* b5  = (const float*)d_in[14];
    const float* w6  = (const float*)d_in[15];
    const float* b6  = (const float*)d_in[16];
    const float* w7  = (const float*)d_in[17];
    const float* b7  = (const float*)d_in[18];
    const float* w8  = (const float*)d_in[19];
    const float* b8  = (const float*)d_in[20];
    u16* ws    = (u16*)d_ws;
    float* out = (float*)d_out;
    int B = in_sizes[0] / 55;

    swz_all<<<36, 256, 0, stream>>>(w1, w3, w2, w4, w5, w7, ws);
    critic_kernel<<<(B + 15) / 16, 256, 0, stream>>>(obs, ag, g, anc, act,
                                                     b1, b2, b3, b4, b5, b7,
                                                     w6, b6, w8, b8, ws, out, B);
}

// Round 12
// 222.587 us; speedup vs baseline: 1.1837x; 1.0262x over previous
//
#include <hip/hip_runtime.h>
#include <hip/hip_bf16.h>

typedef unsigned short u16;
typedef unsigned int   u32;

using bf8 = __attribute__((ext_vector_type(8))) __bf16;
using f4  = __attribute__((ext_vector_type(4))) float;

__device__ __forceinline__ float b2f(u16 u) {
    union { u32 i; float f; } v; v.i = ((u32)u) << 16; return v.f;
}
__device__ __forceinline__ u16 f2b(float f) {
    union { float f; u32 i; } v; v.f = f;
    u32 x = v.i;
    x += 0x7fffu + ((x >> 16) & 1u);   // RNE
    return (u16)(x >> 16);
}
__device__ __forceinline__ u32 pk2(float lo, float hi) {
    union { __hip_bfloat162 h; u32 u; } v;
    v.h = __float22bfloat162_rn(make_float2(lo, hi));
    return v.u;
}

// ---------------------------------------------------------------------------
// Weight swizzle (verified layout, unchanged):
// dst[((kt*16+ct)*64+lane)*8+j] = bf16(W[kt*32+(lane>>4)*8+j][ct*16+(lane&15)])
// ---------------------------------------------------------------------------
__global__ void swz_all(const float* __restrict__ w1, const float* __restrict__ w3,
                        const float* __restrict__ w2, const float* __restrict__ w4,
                        const float* __restrict__ w5, const float* __restrict__ w7,
                        u16* __restrict__ ws) {
    __shared__ u16 slab[32 * 270];
    int b = blockIdx.x, t = threadIdx.x;
    const float* src; u16* dst; int kmax, kt;
    if      (b <  2) { src = w1; dst = ws;          kmax = 54;  kt = b;      }
    else if (b <  4) { src = w3; dst = ws + 16384;  kmax = 54;  kt = b - 2;  }
    else if (b < 12) { src = w2; dst = ws + 32768;  kmax = 256; kt = b - 4;  }
    else if (b < 20) { src = w4; dst = ws + 98304;  kmax = 256; kt = b - 12; }
    else if (b < 28) { src = w5; dst = ws + 163840; kmax = 256; kt = b - 20; }
    else             { src = w7; dst = ws + 229376; kmax = 256; kt = b - 28; }

    #pragma unroll
    for (int it = 0; it < 8; ++it) {
        int flat = it * 1024 + t * 4;
        int row = flat >> 8, col = flat & 255;
        int k = kt * 32 + row;
        float4 v = make_float4(0.f, 0.f, 0.f, 0.f);
        if (k < kmax) v = *(const float4*)(src + k * 256 + col);
        u32* sp = (u32*)&slab[row * 270 + col];
        sp[0] = pk2(v.x, v.y);
        sp[1] = pk2(v.z, v.w);
    }
    __syncthreads();

    int lane = t & 63, wave = t >> 6, lr = lane & 15, kg = lane >> 4;
    #pragma unroll
    for (int i = 0; i < 4; ++i) {
        int ct = wave * 4 + i;
        u16 v[8];
        #pragma unroll
        for (int j = 0; j < 8; ++j)
            v[j] = slab[(kg * 8 + j) * 270 + ct * 16 + lr];
        uint4 o;
        o.x = (u32)v[0] | ((u32)v[1] << 16);
        o.y = (u32)v[2] | ((u32)v[3] << 16);
        o.z = (u32)v[4] | ((u32)v[5] << 16);
        o.w = (u32)v[6] | ((u32)v[7] << 16);
        *(uint4*)(dst + (size_t)(((kt * 16 + ct) * 64 + lane) * 8)) = o;
    }
}

// ---------------------------------------------------------------------------
// Fused critic, dual-stream software pipeline. One WG = 32 batch rows split
// into halves A (rows 0..15) and B (16..31), 16 rows -> 48 phi rows -> rt=3.
// Operand-swapped MFMA (A=weight frags from L2, B=activation b128 from LDS),
// C/D per lane: batch=lane&15, hidden=lg*4+reg (contiguous b64 epilogues).
// Each phase P2..P8 carries TWO independent streams so post-barrier stalls of
// one stream are filled by the other.
// LDS (u16): inpA [0,3456) inpB [3456,6912) hA [6912,19584) hB [19584,32256).
// Overlays: SA=hA rows0..31 (P5), RH0A=hA rows32..47, RH1A=scratch [0,4224);
// SB=hB rows0..31 (P6), RH0B=hB rows32..47, RH1B=hA rows0..15;
// dot partials: A u32[2112..2368), B u32[2368..2624)  (dead inp region).
// ---------------------------------------------------------------------------
#define HS   264
#define HA   6912
#define HB   19584

__device__ __forceinline__ void do_l1(u16* pool, int lane, int wave, int lr, int lg,
                                      const u16* W, const float* bias,
                                      int inpOff, int hOff) {
    f4 acc[3][4];
    #pragma unroll
    for (int rt = 0; rt < 3; ++rt)
        #pragma unroll
        for (int c = 0; c < 4; ++c) acc[rt][c] = (f4){0.f, 0.f, 0.f, 0.f};
    #pragma unroll
    for (int kt = 0; kt < 2; ++kt) {
        bf8 wfr[4];
        #pragma unroll
        for (int c = 0; c < 4; ++c)
            wfr[c] = *(const bf8*)(W + (size_t)(((kt * 16 + wave * 4 + c) * 64 + lane) * 8));
        #pragma unroll
        for (int rt = 0; rt < 3; ++rt) {
            bf8 xfr = *(const bf8*)(&pool[inpOff + (rt * 16 + lr) * 72 + kt * 32 + lg * 8]);
            #pragma unroll
            for (int c = 0; c < 4; ++c)
                acc[rt][c] = __builtin_amdgcn_mfma_f32_16x16x32_bf16(wfr[c], xfr, acc[rt][c], 0, 0, 0);
        }
    }
    #pragma unroll
    for (int c = 0; c < 4; ++c) {
        float4 bv = *(const float4*)(bias + (wave * 4 + c) * 16 + lg * 4);
        #pragma unroll
        for (int rt = 0; rt < 3; ++rt) {
            uint2 w;
            w.x = pk2(fmaxf(acc[rt][c][0] + bv.x, 0.f), fmaxf(acc[rt][c][1] + bv.y, 0.f));
            w.y = pk2(fmaxf(acc[rt][c][2] + bv.z, 0.f), fmaxf(acc[rt][c][3] + bv.w, 0.f));
            *(uint2*)&pool[hOff + (rt * 16 + lr) * HS + (wave * 4 + c) * 16 + lg * 4] = w;
        }
    }
}

__device__ __forceinline__ void do_l2(u16* pool, int lane, int wave, int lr, int lg,
                                      const u16* W, const float* bias,
                                      int hOff, u32 sw[4][2]) {
    f4 acc2[3][4];
    #pragma unroll
    for (int rt = 0; rt < 3; ++rt)
        #pragma unroll
        for (int c = 0; c < 4; ++c) acc2[rt][c] = (f4){0.f, 0.f, 0.f, 0.f};
    #pragma unroll
    for (int ks = 0; ks < 8; ++ks) {
        bf8 wfr[4];
        #pragma unroll
        for (int c = 0; c < 4; ++c)
            wfr[c] = *(const bf8*)(W + (size_t)(((ks * 16 + wave * 4 + c) * 64 + lane) * 8));
        #pragma unroll
        for (int rt = 0; rt < 3; ++rt) {
            bf8 hfr = *(const bf8*)(&pool[hOff + (rt * 16 + lr) * HS + ks * 32 + lg * 8]);
            #pragma unroll
            for (int c = 0; c < 4; ++c)
                acc2[rt][c] = __builtin_amdgcn_mfma_f32_16x16x32_bf16(wfr[c], hfr, acc2[rt][c], 0, 0, 0);
        }
    }
    #pragma unroll
    for (int c = 0; c < 4; ++c) {
        float4 bv = *(const float4*)(bias + (wave * 4 + c) * 16 + lg * 4);
        f4 sv = (f4){0.f, 0.f, 0.f, 0.f};
        #pragma unroll
        for (int p = 0; p < 3; ++p) {
            sv[0] += fmaxf(acc2[p][c][0] + bv.x, 0.f);
            sv[1] += fmaxf(acc2[p][c][1] + bv.y, 0.f);
            sv[2] += fmaxf(acc2[p][c][2] + bv.z, 0.f);
            sv[3] += fmaxf(acc2[p][c][3] + bv.w, 0.f);
        }
        sw[c][0] = pk2(sv[0], sv[1]);
        sw[c][1] = pk2(sv[2], sv[3]);
    }
}

__device__ __forceinline__ void do_swrite(u16* pool, int wave, int lr, int lg,
                                          int sOff, u32 s1[4][2], u32 s2[4][2]) {
    #pragma unroll
    for (int c = 0; c < 4; ++c) {
        int base = sOff + lr * HS + (wave * 4 + c) * 16 + lg * 4;
        *(uint2*)&pool[base]           = *(uint2*)&s1[c][0];
        *(uint2*)&pool[base + 16 * HS] = *(uint2*)&s2[c][0];
    }
}

__device__ __forceinline__ void do_rho(u16* pool, int lane, int wave, int lr, int lg,
                                       const u16* W5, const u16* W7,
                                       const float* b5, const float* b7,
                                       int sOff, int rh0Off, int rh1Off) {
    f4 racc[2][4];
    #pragma unroll
    for (int rt = 0; rt < 2; ++rt)
        #pragma unroll
        for (int c = 0; c < 4; ++c) racc[rt][c] = (f4){0.f, 0.f, 0.f, 0.f};
    #pragma unroll
    for (int ks = 0; ks < 8; ++ks) {
        bf8 w5f[4], w7f[4];
        #pragma unroll
        for (int c = 0; c < 4; ++c) {
            size_t off = (size_t)(((ks * 16 + wave * 4 + c) * 64 + lane) * 8);
            w5f[c] = *(const bf8*)(W5 + off);
            w7f[c] = *(const bf8*)(W7 + off);
        }
        bf8 s1f = *(const bf8*)(&pool[sOff + lr * HS + ks * 32 + lg * 8]);
        bf8 s2f = *(const bf8*)(&pool[sOff + 16 * HS + lr * HS + ks * 32 + lg * 8]);
        #pragma unroll
        for (int c = 0; c < 4; ++c) {
            racc[0][c] = __builtin_amdgcn_mfma_f32_16x16x32_bf16(w5f[c], s1f, racc[0][c], 0, 0, 0);
            racc[1][c] = __builtin_amdgcn_mfma_f32_16x16x32_bf16(w7f[c], s2f, racc[1][c], 0, 0, 0);
        }
    }
    #pragma unroll
    for (int c = 0; c < 4; ++c) {
        float4 bv5 = *(const float4*)(b5 + (wave * 4 + c) * 16 + lg * 4);
        float4 bv7 = *(const float4*)(b7 + (wave * 4 + c) * 16 + lg * 4);
        uint2 w0, w1;
        w0.x = pk2(fmaxf(racc[0][c][0] + bv5.x, 0.f), fmaxf(racc[0][c][1] + bv5.y, 0.f));
        w0.y = pk2(fmaxf(racc[0][c][2] + bv5.z, 0.f), fmaxf(racc[0][c][3] + bv5.w, 0.f));
        w1.x = pk2(fmaxf(racc[1][c][0] + bv7.x, 0.f), fmaxf(racc[1][c][1] + bv7.y, 0.f));
        w1.y = pk2(fmaxf(racc[1][c][2] + bv7.z, 0.f), fmaxf(racc[1][c][3] + bv7.w, 0.f));
        int col = (wave * 4 + c) * 16 + lg * 4;
        *(uint2*)&pool[rh0Off + lr * HS + col] = w0;   // net0 rho-h
        *(uint2*)&pool[rh1Off + lr * HS + col] = w1;   // net1 rho-h
    }
}

__device__ __forceinline__ void do_dotpart(u16* pool, int t,
                                           const float* w6, const float* w8,
                                           int rh0Off, int rh1Off, int partOff) {
    int oidx = t & 31, kc = t >> 5;
    int net = oidx >> 4, r = oidx & 15;
    const float* wv = net ? w8 : w6;
    int base = (net ? rh1Off : rh0Off) + r * HS + kc * 32;
    float s = 0.f;
    #pragma unroll
    for (int it = 0; it < 8; ++it) {
        uint2 two = *(const uint2*)&pool[base + it * 4];
        float4 wq = *(const float4*)(wv + kc * 32 + it * 4);
        s += __uint_as_float(two.x << 16)          * wq.x;
        s += __uint_as_float(two.x & 0xffff0000u)  * wq.y;
        s += __uint_as_float(two.y << 16)          * wq.z;
        s += __uint_as_float(two.y & 0xffff0000u)  * wq.w;
    }
    ((u32*)pool)[partOff + t] = __float_as_uint(s);
}

__device__ __forceinline__ void do_out(u16* pool, int t,
                                       const float* b6, const float* b8,
                                       int partOff, float* out, int bbase, int B) {
    if (t < 32) {
        int net = t >> 4, r = t & 15;
        float qv = net ? b8[0] : b6[0];
        #pragma unroll
        for (int kc = 0; kc < 8; ++kc)
            qv += __uint_as_float(((u32*)pool)[partOff + kc * 32 + t]);
        out[net * B + bbase + r] = qv;
    }
}

__global__ __launch_bounds__(256, 2) void critic_kernel(
    const float* __restrict__ obs, const float* __restrict__ ag,
    const float* __restrict__ g,   const float* __restrict__ anchor,
    const float* __restrict__ act,
    const float* __restrict__ b1,  const float* __restrict__ b2,
    const float* __restrict__ b3,  const float* __restrict__ b4,
    const float* __restrict__ b5,  const float* __restrict__ b7,
    const float* __restrict__ w6,  const float* __restrict__ b6,
    const float* __restrict__ w8,  const float* __restrict__ b8,
    const u16* __restrict__ wsz, float* __restrict__ out, int B) {

    __shared__ u16 pool[6912 + 96 * HS];   // 32256 u16 = 64512 B

    const int t    = threadIdx.x;
    const int lane = t & 63;
    const int wave = t >> 6;
    const int lr   = lane & 15;
    const int lg   = lane >> 4;
    const int wg   = blockIdx.x;

    const u16* W1n0 = wsz;
    const u16* W1n1 = wsz + 16384;
    const u16* W2n0 = wsz + 32768;
    const u16* W2n1 = wsz + 98304;
    const u16* W5   = wsz + 163840;
    const u16* W7   = wsz + 229376;

    // ---- P0: gather both halves (96 threads; 48 rows each half) ----
    if (t < 96) {
        const int O1[3] = {0, 0, 1}, O2[3] = {1, 2, 2};
        const int JA[3] = {3, 4, 6}, KA[3] = {5, 7, 8};
        int half = t >= 48;
        int loc = t - half * 48;
        int p = loc / 16, bl = loc % 16;
        int b = wg * 32 + half * 16 + bl;
        int j = JA[p], k = KA[p];
        bool sel = (anchor[b * 9 + j] - anchor[b * 9 + k]) >= 0.0f;
        int bit2 = sel ? j : k;
        int oi = sel ? O1[p] : O2[p];
        int oj = sel ? O2[p] : O1[p];
        u16* row = &pool[half * 3456 + loc * 72];
        row[0] = f2b(ag[b * 9 + p]);
        row[1] = f2b(ag[b * 9 + bit2]);
        row[2] = f2b(g[b * 9 + p]);
        row[3] = f2b(g[b * 9 + bit2]);
        for (int c = 0; c < 10; ++c) row[4 + c] = f2b(obs[b * 55 + c]);
        const u16 ONE = 0x3F80;
        row[14] = (oi == 0) ? ONE : 0; row[15] = (oi == 1) ? ONE : 0; row[16] = (oi == 2) ? ONE : 0;
        for (int c = 0; c < 15; ++c) row[17 + c] = f2b(obs[b * 55 + 10 + 15 * oi + c]);
        row[32] = (oj == 0) ? ONE : 0; row[33] = (oj == 1) ? ONE : 0; row[34] = (oj == 2) ? ONE : 0;
        for (int c = 0; c < 15; ++c) row[35 + c] = f2b(obs[b * 55 + 10 + 15 * oj + c]);
        for (int c = 0; c < 4; ++c)  row[50 + c] = f2b(act[b * 4 + c]);
        for (int c = 54; c < 64; ++c) row[c] = 0;
    }
    __syncthreads();

    u32 s1wA[4][2], s2wA[4][2], s1wB[4][2], s2wB[4][2];

    // ---- P1: L1 net0 (A) ----
    do_l1(pool, lane, wave, lr, lg, W1n0, b1, 0, HA);
    __syncthreads();

    // ---- P2: L2 net0 (A)  +  L1 net0 (B) ----
    do_l2(pool, lane, wave, lr, lg, W2n0, b2, HA, s1wA);
    do_l1(pool, lane, wave, lr, lg, W1n0, b1, 3456, HB);
    __syncthreads();

    // ---- P3: L1 net1 (A, hA overwrite)  +  L2 net0 (B) ----
    do_l1(pool, lane, wave, lr, lg, W1n1, b3, 0, HA);
    do_l2(pool, lane, wave, lr, lg, W2n0, b2, HB, s1wB);
    __syncthreads();

    // ---- P4: L2 net1 (A)  +  L1 net1 (B, hB overwrite) ----
    do_l2(pool, lane, wave, lr, lg, W2n1, b4, HA, s2wA);
    do_l1(pool, lane, wave, lr, lg, W1n1, b3, 3456, HB);
    __syncthreads();

    // ---- P5: S-write (A -> hA rows0..31)  +  L2 net1 (B) ----
    do_swrite(pool, wave, lr, lg, HA, s1wA, s2wA);
    do_l2(pool, lane, wave, lr, lg, W2n1, b4, HB, s2wB);
    __syncthreads();

    // ---- P6: rho (A): SA -> RH0A (hA rows32..47), RH1A (scratch [0,4224))
    //          +  S-write (B -> hB rows0..31) ----
    do_rho(pool, lane, wave, lr, lg, W5, W7, b5, b7, HA, HA + 32 * HS, 0);
    do_swrite(pool, wave, lr, lg, HB, s1wB, s2wB);
    __syncthreads();

    // ---- P7: dot partials (A)  +  rho (B): SB -> RH0B (hB rows32..47),
    //          RH1B (hA rows0..15) ----
    do_dotpart(pool, t, w6, w8, HA + 32 * HS, 0, 2112);
    do_rho(pool, lane, wave, lr, lg, W5, W7, b5, b7, HB, HB + 32 * HS, HA);
    __syncthreads();

    // ---- P8: out (A)  +  dot partials (B) ----
    do_out(pool, t, b6, b8, 2112, out, wg * 32, B);
    do_dotpart(pool, t, w6, w8, HB + 32 * HS, HA, 2368);
    __syncthreads();

    // ---- P9: out (B) ----
    do_out(pool, t, b6, b8, 2368, out, wg * 32 + 16, B);
}

extern "C" void kernel_launch(void* const* d_in, const int* in_sizes, int n_in,
                              void* d_out, int out_size, void* d_ws, size_t ws_size,
                              hipStream_t stream) {
    const float* obs = (const float*)d_in[0];
    const float* ag  = (const float*)d_in[1];
    const float* g   = (const float*)d_in[2];
    const float* anc = (const float*)d_in[3];
    const float* act = (const float*)d_in[4];
    const float* w1  = (const float*)d_in[5];
    const float* b1  = (const float*)d_in[6];
    const float* w2  = (const float*)d_in[7];
    const float* b2  = (const float*)d_in[8];
    const float* w3  = (const float*)d_in[9];
    const float* b3  = (const float*)d_in[10];
    const float* w4  = (const float*)d_in[11];
    const float* b4  = (const float*)d_in[12];
    const float* w5  = (const float*)d_in[13];
    const float* b5  = (const float*)d_in[14];
    const float* w6  = (const float*)d_in[15];
    const float* b6  = (const float*)d_in[16];
    const float* w7  = (const float*)d_in[17];
    const float* b7  = (const float*)d_in[18];
    const float* w8  = (const float*)d_in[19];
    const float* b8  = (const float*)d_in[20];
    u16* ws    = (u16*)d_ws;
    float* out = (float*)d_out;
    int B = in_sizes[0] / 55;

    swz_all<<<36, 256, 0, stream>>>(w1, w3, w2, w4, w5, w7, ws);
    critic_kernel<<<(B + 31) / 32, 256, 0, stream>>>(obs, ag, g, anc, act,
                                                     b1, b2, b3, b4, b5, b7,
                                                     w6, b6, w8, b8, ws, out, B);
}